// Round 7
// baseline (423.658 us; speedup 1.0000x reference)
//
#include <hip/hip_runtime.h>
#include <hip/hip_bf16.h>
#include <math.h>

// D=4096 K=512 HOP=512 WIN=16384 DX=25 B=128 K2=128 DY=128 K3=256 Y=193 M=128
// ws layout (bytes): same as round 6
//   zxb @0 (3.28MB) | h2b @3,276,800 (12.64MB) | w1b @15,921,152 (32KB)
//   w2f @15,953,920 (1.64MB) | bb @17,592,320 (12.65MB)
//   xh @30,240,768 (4.19MB) | fB @34,435,072 (8.39MB) | part @30,240,768 (aliases)

typedef __attribute__((ext_vector_type(8))) short s8v;       // 8 bf16
typedef __attribute__((ext_vector_type(8))) _Float16 half8;  // 8 fp16
typedef __attribute__((ext_vector_type(16))) float f16v;     // 32x32 acc

__device__ inline ushort f2bf(float f) {
    union { float f; unsigned u; } v; v.f = f;
    unsigned u = v.u;
    return (ushort)((u + 0x7FFFu + ((u >> 16) & 1u)) >> 16);
}

// ---------------- K0x: x -> fp16 ----------------
__global__ void k0x_xh(const float* __restrict__ x, _Float16* __restrict__ xh) {
    int i = blockIdx.x * 256 + threadIdx.x;
    xh[i] = (_Float16)x[i];
}

// ---------------- K0f: filt (4096x1024) -> fp16 tiled [k/8][n][8] ----------------
__global__ __launch_bounds__(256)
void k0f_fB(const float* __restrict__ filt, _Float16* __restrict__ fB) {
    __shared__ float tile[8][257];
    const int t   = threadIdx.x;
    const int n0  = blockIdx.x * 256;
    const int kc8 = blockIdx.y;
    for (int idx = t; idx < 8 * 256; idx += 256) {
        int kk = idx >> 8, n = idx & 255;
        tile[kk][n] = filt[(kc8 * 8 + kk) * 1024 + n0 + n];
    }
    __syncthreads();
    half8 v;
#pragma unroll
    for (int j = 0; j < 8; j++) v[j] = (_Float16)tile[j][t];
    *(half8*)(fB + (size_t)kc8 * 8192 + (size_t)(n0 + t) * 8) = v;
}

// ---------------- K0a: w1 -> bf16 [k2][dy] ----------------
__global__ void k0a_w1b(const float* __restrict__ w1, ushort* __restrict__ w1b) {
    int i = blockIdx.x * 256 + threadIdx.x;
    w1b[i] = f2bf(w1[i]);
}

// ---------------- K0b: w2 -> bf16 frag-tiled [dx][ks][q][k3][j], k2=16ks+8q+j ----------------
__global__ void k0b_w2f(const float* __restrict__ w2, ushort* __restrict__ w2f) {
    int i = blockIdx.x * 256 + threadIdx.x;   // 0..819199
    int j  = i & 7;
    int k3 = (i >> 3) & 255;
    int q  = (i >> 11) & 1;
    int ks = (i >> 12) & 7;
    int dx = i >> 15;
    int k2 = 16 * ks + 8 * q + j;
    w2f[i] = f2bf(w2[(k3 * 128 + k2) * 25 + dx]);
}

// ---------------- K0c: beta -> bf16 ----------------
__global__ void k0c_bb(const float* __restrict__ beta, ushort* __restrict__ bb) {
    int i = blockIdx.x * 256 + threadIdx.x;
    bb[i] = f2bf(beta[i]);
}

// ---------------- K1 v2: spec GEMM, tile 128x64, grid 400, 1 barrier/iter ----------------
__global__ __launch_bounds__(256)
void k1_mfma(const _Float16* __restrict__ xh, const _Float16* __restrict__ fB,
             ushort* __restrict__ zxb) {
    __shared__ _Float16 Al[2 * 4096];   // ping-pong: [p][s][row][q*8], 16 KB
    const int t  = threadIdx.x;
    const int n0 = blockIdx.x * 64;
    const int m0 = blockIdx.y * 128;
    const int w  = t >> 6, l = t & 63;
    const int wm = 32 * w;
    const int qf = l >> 5;
    const int ml = l & 31;

    const int srow = t >> 1;
    const int sq   = t & 1;
    const int gm   = m0 + srow;
    const _Float16* apt = xh + (gm / 25) * 16384 + (gm % 25) * 512 + sq * 8;
    half8* Als8 = (half8*)Al;

    const _Float16* pB = fB + (size_t)qf * 8192 + (size_t)(n0 + ml) * 8;

    f16v acc[2];
#pragma unroll
    for (int nt = 0; nt < 2; nt++)
#pragma unroll
        for (int r = 0; r < 16; r++) acc[nt][r] = 0.f;

    half8 v0 = *(const half8*)(apt);
    half8 v1 = *(const half8*)(apt + 16);

    for (int kb = 0; kb < 128; kb++) {
        const int p = kb & 1;
        Als8[p * 512 + t]       = v0;
        Als8[p * 512 + 256 + t] = v1;
        __syncthreads();
        if (kb < 127) {
            v0 = *(const half8*)(apt + (kb + 1) * 32);
            v1 = *(const half8*)(apt + (kb + 1) * 32 + 16);
        }
#pragma unroll
        for (int s = 0; s < 2; s++) {
            half8 a0 = *(const half8*)((const char*)Al + p * 8192 + s * 4096 + (wm + ml) * 32 + qf * 16);
            const _Float16* pBk = pB + ((size_t)kb * 2 + s) * 16384;
            half8 b0 = *(const half8*)(pBk);
            half8 b1 = *(const half8*)(pBk + 256);
            acc[0] = __builtin_amdgcn_mfma_f32_32x32x16_f16(a0, b0, acc[0], 0, 0, 0);
            acc[1] = __builtin_amdgcn_mfma_f32_32x32x16_f16(a0, b1, acc[1], 0, 0, 0);
        }
    }

#pragma unroll
    for (int nt = 0; nt < 2; nt++) {
#pragma unroll
        for (int r = 0; r < 16; r++) {
            float val = acc[nt][r];
            float oth = __shfl_xor(val, 1, 64);
            if (!(l & 1)) {
                float pw = fmaf(val, val, fmaf(oth, oth, 1e-14f));
                int m = m0 + wm + 4 * qf + (r & 3) + 8 * (r >> 2);
                int n = n0 + nt * 32 + ml;
                zxb[m * 512 + (n >> 1)] = f2bf(logf(pw));
            }
        }
    }
}

// ---------------- K2 v5: fused conv1+conv2, 2 dx per barrier, 4 acc chains ----------------
// grid (7 yt, 128 b), 256 threads = 4 waves (u = k-quarter). 13 barriers.
// accL accumulates even dx, accR odd dx; summed at epilogue.
__global__ __launch_bounds__(256)
void k2_mfma(const ushort* __restrict__ zxb, const ushort* __restrict__ w1b,
             const ushort* __restrict__ w2f, ushort* __restrict__ h2b) {
    __shared__ ushort h1l[2 * 2 * 16 * 32 * 8];   // 32 KB: [P][d][k2/8][yy][8]
    const int t  = threadIdx.x;
    const int yt = blockIdx.x;      // 0..6
    const int b  = blockIdx.y;
    const int y0 = yt * 32;
    const int u  = t >> 6;
    const int l  = t & 63;
    const int yy = l & 31;
    const int q  = l >> 5;
    const int y  = y0 + yy;

    // persistent conv1 A-frags: k2-tile [32u, 32u+32)
    s8v w1f[8];
    {
        const ushort* wp = w1b + (32 * u + yy) * 128 + 8 * q;
#pragma unroll
        for (int ks = 0; ks < 8; ks++)
            w1f[ks] = *(const s8v*)(wp + 16 * ks);
    }

    const ushort* zb = zxb + (size_t)b * 12800 + 2 * y + 8 * q;
    const ushort* wa = w2f + (size_t)q * 2048 + (size_t)(64 * u + yy) * 8;

    f16v accL[2], accR[2];
#pragma unroll
    for (int mt = 0; mt < 2; mt++)
#pragma unroll
        for (int r = 0; r < 16; r++) { accL[mt][r] = 0.f; accR[mt][r] = 0.f; }

    for (int c = 0; c < 13; c++) {
        const int P = c & 1;
        const int dx0 = 2 * c, dx1 = 2 * c + 1;
        const bool have1 = (c < 12);

        // ---- conv1: two independent 8-MFMA chains ----
        const ushort* zp0 = zb + dx0 * 512;
        const ushort* zp1 = zb + dx1 * 512;
        f16v a10, a11;
#pragma unroll
        for (int r = 0; r < 16; r++) { a10[r] = 0.f; a11[r] = 0.f; }
#pragma unroll
        for (int ks = 0; ks < 8; ks++) {
            s8v bf0 = *(const s8v*)(zp0 + 16 * ks);
            a10 = __builtin_amdgcn_mfma_f32_32x32x16_bf16(w1f[ks], bf0, a10, 0, 0, 0);
            if (have1) {
                s8v bf1 = *(const s8v*)(zp1 + 16 * ks);
                a11 = __builtin_amdgcn_mfma_f32_32x32x16_bf16(w1f[ks], bf1, a11, 0, 0, 0);
            }
        }
        // ---- relu + pack both dx ----
#pragma unroll
        for (int g = 0; g < 4; g++) {
            unsigned p0 = (unsigned)f2bf(fmaxf(a10[4 * g + 0], 0.f))
                        | ((unsigned)f2bf(fmaxf(a10[4 * g + 1], 0.f)) << 16);
            unsigned p1 = (unsigned)f2bf(fmaxf(a10[4 * g + 2], 0.f))
                        | ((unsigned)f2bf(fmaxf(a10[4 * g + 3], 0.f)) << 16);
            unsigned* dst = (unsigned*)(h1l + (((P * 2 + 0) * 16 + 4 * u + g) * 32 + yy) * 8 + 4 * q);
            dst[0] = p0; dst[1] = p1;
        }
        if (have1) {
#pragma unroll
            for (int g = 0; g < 4; g++) {
                unsigned p0 = (unsigned)f2bf(fmaxf(a11[4 * g + 0], 0.f))
                            | ((unsigned)f2bf(fmaxf(a11[4 * g + 1], 0.f)) << 16);
                unsigned p1 = (unsigned)f2bf(fmaxf(a11[4 * g + 2], 0.f))
                            | ((unsigned)f2bf(fmaxf(a11[4 * g + 3], 0.f)) << 16);
                unsigned* dst = (unsigned*)(h1l + (((P * 2 + 1) * 16 + 4 * u + g) * 32 + yy) * 8 + 4 * q);
                dst[0] = p0; dst[1] = p1;
            }
        }
        __syncthreads();
        // ---- conv2: 4 independent chains (accL x2, accR x2) ----
        const ushort* ap0 = wa + (size_t)dx0 * 32768;
        const ushort* ap1 = wa + (size_t)dx1 * 32768;
#pragma unroll
        for (int ks = 0; ks < 8; ks++) {
            s8v hb0 = *(const s8v*)(h1l + (((P * 2 + 0) * 16 + 2 * ks + q) * 32 + yy) * 8);
            s8v a00 = *(const s8v*)(ap0 + (size_t)ks * 4096);
            s8v a01 = *(const s8v*)(ap0 + (size_t)ks * 4096 + 256);
            accL[0] = __builtin_amdgcn_mfma_f32_32x32x16_bf16(a00, hb0, accL[0], 0, 0, 0);
            accL[1] = __builtin_amdgcn_mfma_f32_32x32x16_bf16(a01, hb0, accL[1], 0, 0, 0);
            if (have1) {
                s8v hb1 = *(const s8v*)(h1l + (((P * 2 + 1) * 16 + 2 * ks + q) * 32 + yy) * 8);
                s8v a10f = *(const s8v*)(ap1 + (size_t)ks * 4096);
                s8v a11f = *(const s8v*)(ap1 + (size_t)ks * 4096 + 256);
                accR[0] = __builtin_amdgcn_mfma_f32_32x32x16_bf16(a10f, hb1, accR[0], 0, 0, 0);
                accR[1] = __builtin_amdgcn_mfma_f32_32x32x16_bf16(a11f, hb1, accR[1], 0, 0, 0);
            }
        }
    }

    // ---- epilogue: combine chains, relu, store ----
    if (y < 193) {
#pragma unroll
        for (int mt = 0; mt < 2; mt++) {
#pragma unroll
            for (int r = 0; r < 16; r++) {
                float v = accL[mt][r] + accR[mt][r];
                int k3 = 64 * u + 32 * mt + (r & 3) + 8 * (r >> 2) + 4 * q;
                h2b[((size_t)b * 256 + k3) * 193 + y] = f2bf(fmaxf(v, 0.f));
            }
        }
    }
}

// ---------------- K4: y partials via bf16 MFMA, 193-way k-split ----------------
__global__ __launch_bounds__(256)
void k4_mfma(const ushort* __restrict__ h2b, const ushort* __restrict__ bb,
             float* __restrict__ part) {
    const int t = threadIdx.x, w = t >> 6, l = t & 63;
    const int s = blockIdx.x;
    const int kb = s * 256;
    const int qf = l >> 5;
    const int ml = l & 31;
    const ushort* pa  = h2b + (size_t)(w * 32 + ml) * 49408 + kb + qf * 8;
    const ushort* pb0 = bb  + (size_t)ml * 49408 + kb + qf * 8;

    f16v acc[4];
#pragma unroll
    for (int nt = 0; nt < 4; nt++)
#pragma unroll
        for (int r = 0; r < 16; r++) acc[nt][r] = 0.f;

    for (int ks = 0; ks < 16; ks++) {
        s8v af = *(const s8v*)(pa + ks * 16);
#pragma unroll
        for (int nt = 0; nt < 4; nt++) {
            s8v bf = *(const s8v*)(pb0 + (size_t)nt * 32 * 49408 + ks * 16);
            acc[nt] = __builtin_amdgcn_mfma_f32_32x32x16_bf16(af, bf, acc[nt], 0, 0, 0);
        }
    }
    float* pp = part + (size_t)s * 16384;
#pragma unroll
    for (int nt = 0; nt < 4; nt++)
#pragma unroll
        for (int r = 0; r < 16; r++) {
            int m = w * 32 + 4 * qf + (r & 3) + 8 * (r >> 2);
            pp[m * 128 + nt * 32 + ml] = acc[nt][r];
        }
}

// ---------------- K5: reduce 193 partials ----------------
__global__ void k5_red(const float* __restrict__ part, float* __restrict__ out) {
    int i = blockIdx.x * 256 + threadIdx.x;
    float s = 0.f;
    for (int k = 0; k < 193; k++) s += part[(size_t)k * 16384 + i];
    out[i] = s;
}

extern "C" void kernel_launch(void* const* d_in, const int* in_sizes, int n_in,
                              void* d_out, int out_size, void* d_ws, size_t ws_size,
                              hipStream_t stream) {
    const float* x    = (const float*)d_in[0];
    const float* filt = (const float*)d_in[1];
    const float* w1   = (const float*)d_in[2];
    const float* w2   = (const float*)d_in[3];
    const float* beta = (const float*)d_in[4];
    float* out = (float*)d_out;

    char* ws = (char*)d_ws;
    ushort*   zxb  = (ushort*)(ws + 0);
    ushort*   h2b  = (ushort*)(ws + 3276800);
    ushort*   w1b  = (ushort*)(ws + 15921152);
    ushort*   w2f  = (ushort*)(ws + 15953920);
    ushort*   bb   = (ushort*)(ws + 17592320);
    _Float16* xh   = (_Float16*)(ws + 30240768);
    _Float16* fB   = (_Float16*)(ws + 34435072);
    float*    part = (float*)(ws + 30240768);

    k0x_xh<<<8192, 256, 0, stream>>>(x, xh);
    k0f_fB<<<dim3(4, 512), 256, 0, stream>>>(filt, fB);
    k0a_w1b<<<64, 256, 0, stream>>>(w1, w1b);
    k0b_w2f<<<3200, 256, 0, stream>>>(w2, w2f);
    k0c_bb<<<24704, 256, 0, stream>>>(beta, bb);
    k1_mfma<<<dim3(16, 25), 256, 0, stream>>>(xh, fB, zxb);
    k2_mfma<<<dim3(7, 128), 256, 0, stream>>>(zxb, w1b, w2f, h2b);
    k4_mfma<<<193, 256, 0, stream>>>(h2b, bb, part);
    k5_red<<<64, 256, 0, stream>>>(part, out);
}